// Round 8
// baseline (728.387 us; speedup 1.0000x reference)
//
#include <hip/hip_runtime.h>
#include <hip/hip_bf16.h>
#include <cstdint>

using u16 = unsigned short;
typedef short s16x8 __attribute__((ext_vector_type(8)));
typedef float f32x4 __attribute__((ext_vector_type(4)));

// ---------- helpers ----------
__device__ __forceinline__ float b2f(u16 b) {
    union { unsigned u; float f; } z; z.u = ((unsigned)b) << 16; return z.f;
}
__device__ __forceinline__ u16 f2b(float f) {
    union { float f; unsigned u; } z; z.f = f;
    return (u16)((z.u + 0x7fffu + ((z.u >> 16) & 1u)) >> 16);
}
__device__ __forceinline__ float gelu_f(float x) {
    return 0.5f * x * (1.0f + erff(x * 0.70710678118654752440f));
}
__device__ __forceinline__ void gl2lds16(const void* g, void* l) {
    __builtin_amdgcn_global_load_lds(
        (const __attribute__((address_space(1))) void*)g,
        (__attribute__((address_space(3))) void*)l, 16, 0, 0);
}

enum { F_BIAS = 1, F_GELU = 2, F_RANK3 = 4, F_RESIDH = 8,
       F_DEG = 16, F_OUTF = 32, F_OUTH = 64 };

// ---------- 256x256 GEMM, K=512: C = epilogue(A_bf16[M x 512] @ Bt_bf16[N x 512]^T)
// 8 waves (2M x 4N), per-wave 128x64 output, BK=64, double-buffered 128 KiB LDS.
// T2: LDS rows are 128 B (8 x 16B chunks); chunk index XOR'd with (row&7) so a
//     wave's ds_read_b128 spreads all 32 banks. global_load_lds writes linearly,
//     so the swizzle is applied by pre-swizzling the per-lane GLOBAL source
//     (rule #21: both-sides-or-neither).
// T3(min): next K-tile's 8 loads issue BEFORE this tile's compute; the single
//     __syncthreads per tile drains them (compiler emits vmcnt(0) at barrier).
// T5: setprio(1) around each 16-MFMA cluster.
// T1: bijective XCD swizzle on flat grid; rowblk = swz>>gxShift.
template<int EPI>
__global__ __launch_bounds__(512, 2) void gemm256_k(
    const u16* __restrict__ A, const u16* __restrict__ Bt,
    float* __restrict__ Cf, u16* __restrict__ Ch,
    const u16* __restrict__ srcH,
    const float* __restrict__ bias, const float* __restrict__ bias2,
    const int* __restrict__ deg, const float* __restrict__ river,
    const float* __restrict__ w1tail, int Mreal, int ldh, int gxShift)
{
    __shared__ __align__(16) u16 smem[2][2][256 * 64];   // 128 KiB

    const int nwg  = gridDim.x;
    const int orig = blockIdx.x;
    const int xcd  = orig & 7;
    const int i8   = orig >> 3;
    const int q    = nwg >> 3;
    const int rm   = nwg & 7;
    const int swz  = (xcd < rm) ? (xcd * (q + 1) + i8)
                                : (rm * (q + 1) + (xcd - rm) * q + i8);
    const int rowblk = swz >> gxShift;
    const int colblk = swz & ((1 << gxShift) - 1);

    const int tid  = threadIdx.x;
    const int lane = tid & 63;
    const int w    = tid >> 6;     // 0..7
    const int wr   = w >> 2;       // 0..1 (M half)
    const int wc   = w & 3;        // 0..3 (N quarter)
    const int fr   = lane & 15;
    const int fq   = lane >> 4;

    // staging: linear LDS position of this lane -> (row, chunk); the data that
    // belongs there is global chunk' = chunk ^ (row&7).
    const int  srow  = (w << 3) + (lane >> 3);                    // row within 64-row slab
    const long schnk = (long)(((lane & 7) ^ ((lane >> 3) & 7)) << 3); // elem offset
    const long abase = (long)rowblk * 256 + srow;
    const long bbase = (long)colblk * 256 + srow;

    auto STAGE = [&](int buf, int kt) {
        u16* la = &smem[buf][0][0] + (w << 9);   // wave-uniform LDS base
        u16* lb = &smem[buf][1][0] + (w << 9);
        const long ko = (long)kt * 64 + schnk;
#pragma unroll
        for (int j = 0; j < 4; j++) {
            gl2lds16(A  + (abase + j * 64) * 512 + ko, la + j * 4096);
            gl2lds16(Bt + (bbase + j * 64) * 512 + ko, lb + j * 4096);
        }
    };

    f32x4 acc[8][4];
#pragma unroll
    for (int m = 0; m < 8; m++)
#pragma unroll
        for (int n = 0; n < 4; n++) { f32x4 z = {0.f, 0.f, 0.f, 0.f}; acc[m][n] = z; }

    STAGE(0, 0);
    __syncthreads();                        // vmcnt(0) drain at barrier

    for (int kt = 0; kt < 8; kt++) {
        const int cur = kt & 1;
        if (kt < 7) STAGE(cur ^ 1, kt + 1); // issue-early: covered by compute below
        const u16* Ab = &smem[cur][0][0];
        const u16* Bb = &smem[cur][1][0];
#pragma unroll
        for (int ks = 0; ks < 2; ks++) {
            const int sc = ((((ks << 2) + fq) ^ (fr & 7)) << 3);  // swizzled chunk, elems
            s16x8 bf[4], af[4];
#pragma unroll
            for (int n = 0; n < 4; n++)
                bf[n] = *(const s16x8*)(Bb + (((wc << 6) + (n << 4) + fr) << 6) + sc);
#pragma unroll
            for (int m = 0; m < 4; m++)
                af[m] = *(const s16x8*)(Ab + (((wr << 7) + (m << 4) + fr) << 6) + sc);
            __builtin_amdgcn_s_setprio(1);
#pragma unroll
            for (int m = 0; m < 4; m++)
#pragma unroll
                for (int n = 0; n < 4; n++)
                    acc[m][n] = __builtin_amdgcn_mfma_f32_16x16x32_bf16(af[m], bf[n], acc[m][n], 0, 0, 0);
            __builtin_amdgcn_s_setprio(0);
#pragma unroll
            for (int m = 0; m < 4; m++)
                af[m] = *(const s16x8*)(Ab + (((wr << 7) + ((m + 4) << 4) + fr) << 6) + sc);
            __builtin_amdgcn_s_setprio(1);
#pragma unroll
            for (int m = 0; m < 4; m++)
#pragma unroll
                for (int n = 0; n < 4; n++)
                    acc[m + 4][n] = __builtin_amdgcn_mfma_f32_16x16x32_bf16(af[m], bf[n], acc[m + 4][n], 0, 0, 0);
            __builtin_amdgcn_s_setprio(0);
        }
        __syncthreads();                    // drains next tile's loads; buffer swap safe
    }

    // ---------- epilogue ----------
    const int colbase = (colblk << 8) + (wc << 6);
#pragma unroll
    for (int m = 0; m < 8; m++) {
        const int row0 = (rowblk << 8) + (wr << 7) + (m << 4) + (fq << 2);
#pragma unroll
        for (int rI = 0; rI < 4; rI++) {
            const int rr = row0 + rI;
            const bool real = rr < Mreal;
            float rv0 = 0.f, rv1 = 0.f, rv2 = 0.f;
            if constexpr (EPI & F_RANK3) {
                if (real) { rv0 = river[rr * 3]; rv1 = river[rr * 3 + 1]; rv2 = river[rr * 3 + 2]; }
            }
            float dg = 0.f;
            if constexpr (EPI & F_DEG) { if (real) dg = (float)deg[rr]; }
#pragma unroll
            for (int n = 0; n < 4; n++) {
                const int col = colbase + (n << 4) + fr;
                float v = acc[m][n][rI];
                if constexpr (EPI & F_BIAS)   v += bias[col];
                if constexpr (EPI & F_RANK3)  v += rv0 * w1tail[col] + rv1 * w1tail[512 + col] + rv2 * w1tail[1024 + col];
                if constexpr (EPI & F_GELU)   v = gelu_f(v);
                if constexpr (EPI & F_RESIDH) v += b2f(srcH[(long)rr * 512 + col]);
                if constexpr (EPI & F_DEG)    v += dg * bias2[col];
                if constexpr (EPI & F_OUTF)   { if (real) Cf[(long)rr * 512 + col] = v; }
                if constexpr (EPI & F_OUTH)   Ch[(long)rr * ldh + col] = f2b(v);
            }
        }
    }
}

// ---------- CSR build ----------
__global__ __launch_bounds__(256) void deg_k(const int* __restrict__ ed, int* __restrict__ deg, int nE)
{
    const int e = blockIdx.x * 256 + threadIdx.x;
    if (e < nE) atomicAdd(&deg[ed[2 * e + 1]], 1);
}

__global__ __launch_bounds__(256) void scan1_k(
    const int* __restrict__ deg, int* __restrict__ rowptr,
    int* __restrict__ partials, int n)
{
    __shared__ int tmp[256];
    const int tid = threadIdx.x;
    const int gid = blockIdx.x * 256 + tid;
    const int v = (gid < n) ? deg[gid] : 0;
    tmp[tid] = v;
    __syncthreads();
#pragma unroll
    for (int ofs = 1; ofs < 256; ofs <<= 1) {
        int t = (tid >= ofs) ? tmp[tid - ofs] : 0;
        __syncthreads();
        tmp[tid] += t;
        __syncthreads();
    }
    if (gid < n) rowptr[gid] = tmp[tid] - v;
    if (tid == 255) partials[blockIdx.x] = tmp[255];
}

__global__ __launch_bounds__(256) void scan2_k(int* __restrict__ partials, int nb)
{
    __shared__ int tmp[256];
    const int tid = threadIdx.x;
    const int v = (tid < nb) ? partials[tid] : 0;
    tmp[tid] = v;
    __syncthreads();
#pragma unroll
    for (int ofs = 1; ofs < 256; ofs <<= 1) {
        int t = (tid >= ofs) ? tmp[tid - ofs] : 0;
        __syncthreads();
        tmp[tid] += t;
        __syncthreads();
    }
    if (tid < nb) partials[tid] = tmp[tid] - v;
}

__global__ __launch_bounds__(256) void scan3_k(
    int* __restrict__ rowptr, const int* __restrict__ partials, int n)
{
    const int gid = blockIdx.x * 256 + threadIdx.x;
    if (gid < n) rowptr[gid] += partials[blockIdx.x];
}

__global__ __launch_bounds__(256) void scat_k(
    const int* __restrict__ ed, const int* __restrict__ rowptr,
    int* __restrict__ cursor, int* __restrict__ csr, int nE)
{
    const int e = blockIdx.x * 256 + threadIdx.x;
    if (e >= nE) return;
    const int t = ed[2 * e + 1];
    const int p = atomicAdd(&cursor[t], 1);
    csr[rowptr[t] + p] = ed[2 * e];
}

// ---------- gather: Hg[t] = bf16( sum_{s in in(t)} gelu(A[s] + B[t] + bm1) ) ----------
__global__ __launch_bounds__(256) void gather_k(
    const int* __restrict__ rowptr, const int* __restrict__ degv,
    const int* __restrict__ csr, const u16* __restrict__ AB,
    const float* __restrict__ bm1, u16* __restrict__ Hg, int nNodes)
{
    const int t = (blockIdx.x << 2) + (threadIdx.x >> 6);
    if (t >= nNodes) return;
    const int lane = threadIdx.x & 63;
    const int c = lane << 3;
    float acc[8] = {0.f, 0.f, 0.f, 0.f, 0.f, 0.f, 0.f, 0.f};
    const int d = degv[t];
    if (d > 0) {
        s16x8 bv = *(const s16x8*)(AB + (long)t * 1024 + 512 + c);
        const float4* bmv = (const float4*)(bm1 + c);
        float4 q0 = bmv[0], q1 = bmv[1];
        float base[8] = { q0.x, q0.y, q0.z, q0.w, q1.x, q1.y, q1.z, q1.w };
#pragma unroll
        for (int j = 0; j < 8; j++) base[j] += b2f((u16)bv[j]);
        const int p0 = rowptr[t];
        for (int i = 0; i < d; i++) {
            const int s = csr[p0 + i];
            s16x8 av = *(const s16x8*)(AB + (long)s * 1024 + c);
#pragma unroll
            for (int j = 0; j < 8; j++) acc[j] += gelu_f(b2f((u16)av[j]) + base[j]);
        }
    }
    s16x8 o;
#pragma unroll
    for (int j = 0; j < 8; j++) o[j] = (short)f2b(acc[j]);
    *(s16x8*)(Hg + (long)t * 512 + c) = o;
}

// ---------- f32 -> bf16 (flat, region beyond nSrc zero-filled) ----------
__global__ __launch_bounds__(256) void cvt_pad_k(
    const float* __restrict__ src, u16* __restrict__ dst, long nSrc, long nTot)
{
    const long i = ((long)blockIdx.x * 256 + threadIdx.x) * 8;
    if (i >= nTot) return;
    s16x8 v;
    if (i + 8 <= nSrc) {
        const float4* s4 = (const float4*)(src + i);
        float4 a = s4[0], b = s4[1];
        v[0] = (short)f2b(a.x); v[1] = (short)f2b(a.y); v[2] = (short)f2b(a.z); v[3] = (short)f2b(a.w);
        v[4] = (short)f2b(b.x); v[5] = (short)f2b(b.y); v[6] = (short)f2b(b.z); v[7] = (short)f2b(b.w);
    } else {
#pragma unroll
        for (int j = 0; j < 8; j++) v[j] = (i + j < nSrc) ? (short)f2b(src[i + j]) : (short)0;
    }
    *(s16x8*)(dst + i) = v;
}

// ---------- weight transpose + convert: Wt[n*K+k] = bf16(W[(k+off)*N + n]) ----------
__global__ __launch_bounds__(256) void wtrans_k(
    const float* __restrict__ W, u16* __restrict__ Wt, int K, int N, int rowOff)
{
    const int idx = blockIdx.x * 256 + threadIdx.x;
    if (idx >= K * N) return;
    const int n = idx / K, k = idx % K;
    Wt[idx] = f2b(W[(long)(k + rowOff) * N + n]);
}

extern "C" void kernel_launch(void* const* d_in, const int* in_sizes, int n_in,
                              void* d_out, int out_size, void* d_ws, size_t ws_size,
                              hipStream_t stream)
{
    const float* nodef = (const float*)d_in[0];
    const float* river = (const float*)d_in[1];
    const int*   edges = (const int*)d_in[2];
    const float* W1  = (const float*)d_in[3];
    const float* b1  = (const float*)d_in[4];
    const float* W2  = (const float*)d_in[5];
    const float* b2  = (const float*)d_in[6];
    const float* Wm1 = (const float*)d_in[7];
    const float* bm1 = (const float*)d_in[8];
    const float* Wm2 = (const float*)d_in[9];
    const float* bm2 = (const float*)d_in[10];
    float* out = (float*)d_out;
    (void)n_in; (void)out_size;

    const int M = 50000, Mpad = 50176, H = 512;      // 196 x 256 row-tiles
    const int nE = in_sizes[2] / 2;
    const size_t nElem = (size_t)Mpad * H;           // 25,690,112
    const size_t nOut  = (size_t)M * H;

    char* ws = (char*)d_ws;
    size_t off = 0;
    auto alloc = [&](size_t bytes) { void* p = ws + off; off += (bytes + 255) & ~(size_t)255; return p; };
    u16* feats16 = (u16*)alloc(nElem * 2);            // running features (bf16 residual carrier)
    u16* AB16    = (u16*)alloc(nElem * 4);            // [Mpad][1024]: A | B (nf16 early)
    u16* Hg16    = (u16*)alloc(nElem * 2);            // gather output / h1
    u16* W1t     = (u16*)alloc(512 * 512 * 2);
    u16* W2t     = (u16*)alloc(512 * 512 * 2);
    u16* Wm1ct   = (u16*)alloc(1024 * 512 * 2);
    u16* Wm2t    = (u16*)alloc(512 * 512 * 2);
    int* deg     = (int*)alloc((size_t)Mpad * 4);
    int* rowptr  = (int*)alloc((size_t)Mpad * 4);
    int* cursor  = (int*)alloc((size_t)Mpad * 4);
    int* csr     = (int*)alloc((size_t)nE * 4);
    int* partials= (int*)alloc(256 * 4);
    const size_t NEED = off;                          // ~210 MB (209 MB confirmed fits)

    if (ws_size < NEED) return;                       // tripwire: clean absmax fail

    const int scanBlocks = Mpad / 256;                // 196 exact
    const dim3 g512(scanBlocks * 2, 1, 1);            // 392 blocks, gxShift=1
    const dim3 g1024(scanBlocks * 4, 1, 1);           // 784 blocks, gxShift=2
    const dim3 gblk(256, 1, 1);
    const dim3 gblk512(512, 1, 1);
    const int cvtBlocks = (int)(nElem / 8 / 256);     // 12544 exact

    // CSR build (edges fixed; rebuilt every call for determinism)
    hipMemsetAsync(deg, 0, (size_t)Mpad * 4, stream);
    hipMemsetAsync(cursor, 0, (size_t)Mpad * 4, stream);
    deg_k<<<dim3((nE + 255) / 256), gblk, 0, stream>>>(edges, deg, nE);
    scan1_k<<<dim3(scanBlocks), gblk, 0, stream>>>(deg, rowptr, partials, Mpad);
    scan2_k<<<dim3(1), gblk, 0, stream>>>(partials, scanBlocks);
    scan3_k<<<dim3(scanBlocks), gblk, 0, stream>>>(rowptr, partials, Mpad);
    scat_k<<<dim3((nE + 255) / 256), gblk, 0, stream>>>(edges, rowptr, cursor, csr, nE);

    // weights -> transposed bf16
    wtrans_k<<<dim3(1024), gblk, 0, stream>>>(W1,  W1t,             512, 512, 0);
    wtrans_k<<<dim3(1024), gblk, 0, stream>>>(W2,  W2t,             512, 512, 0);
    wtrans_k<<<dim3(1024), gblk, 0, stream>>>(Wm1, Wm1ct,           512, 512, 0);
    wtrans_k<<<dim3(1024), gblk, 0, stream>>>(Wm1, Wm1ct + 512*512, 512, 512, 512);
    wtrans_k<<<dim3(1024), gblk, 0, stream>>>(Wm2, Wm2t,            512, 512, 0);

    // node_features -> bf16 (flat [Mpad][512] in AB16 first half, padded rows zero)
    cvt_pad_k<<<dim3(cvtBlocks), gblk, 0, stream>>>(nodef, AB16, (long)nOut, (long)nElem);

    // h1 = gelu(x @ W1 + b1 + river @ W1tail) -> Hg16
    gemm256_k<F_BIAS | F_RANK3 | F_GELU | F_OUTH><<<g512, gblk512, 0, stream>>>(
        AB16, W1t, nullptr, Hg16, nullptr, b1, nullptr, nullptr, river, W1 + 512 * 512, M, 512, 1);
    // feats16 = h1 @ W2 + b2  (bf16 only)
    gemm256_k<F_BIAS | F_OUTH><<<g512, gblk512, 0, stream>>>(
        Hg16, W2t, nullptr, feats16, nullptr, b2, nullptr, nullptr, nullptr, nullptr, M, 512, 1);

    for (int r = 0; r < 3; r++) {
        // AB = feats @ [Wm1_top | Wm1_bot]  (N=1024 combined)
        gemm256_k<F_OUTH><<<g1024, gblk512, 0, stream>>>(
            feats16, Wm1ct, nullptr, AB16, nullptr, nullptr, nullptr, nullptr, nullptr, nullptr, M, 1024, 2);
        // Hg[t] = sum_in gelu(A[s] + B[t] + bm1)
        gather_k<<<dim3(Mpad / 4), gblk, 0, stream>>>(rowptr, deg, csr, AB16, bm1, Hg16, Mpad);
        // feats = feats + Hg @ Wm2 + deg * bm2
        if (r < 2)
            gemm256_k<F_RESIDH | F_DEG | F_OUTH><<<g512, gblk512, 0, stream>>>(
                Hg16, Wm2t, nullptr, feats16, feats16, nullptr, bm2, deg, nullptr, nullptr, M, 512, 1);
        else
            gemm256_k<F_RESIDH | F_DEG | F_OUTF><<<g512, gblk512, 0, stream>>>(
                Hg16, Wm2t, out, nullptr, feats16, nullptr, bm2, deg, nullptr, nullptr, M, 512, 1);
    }
}

// Round 10
// 690.138 us; speedup vs baseline: 1.0554x; 1.0554x over previous
//
#include <hip/hip_runtime.h>
#include <hip/hip_bf16.h>
#include <cstdint>

using u16 = unsigned short;
typedef short s16x8 __attribute__((ext_vector_type(8)));
typedef float f32x4 __attribute__((ext_vector_type(4)));

// ---------- helpers ----------
__device__ __forceinline__ float b2f(u16 b) {
    union { unsigned u; float f; } z; z.u = ((unsigned)b) << 16; return z.f;
}
__device__ __forceinline__ u16 f2b(float f) {
    union { float f; unsigned u; } z; z.f = f;
    return (u16)((z.u + 0x7fffu + ((z.u >> 16) & 1u)) >> 16);
}
__device__ __forceinline__ float gelu_f(float x) {
    return 0.5f * x * (1.0f + erff(x * 0.70710678118654752440f));
}
__device__ __forceinline__ void gl2lds16(const void* g, void* l) {
    __builtin_amdgcn_global_load_lds(
        (const __attribute__((address_space(1))) void*)g,
        (__attribute__((address_space(3))) void*)l, 16, 0, 0);
}

enum { F_BIAS = 1, F_GELU = 2, F_RANK3 = 4, F_RESIDH = 8,
       F_DEG = 16, F_OUTF = 32, F_OUTH = 64 };

// ---------- GEMM (R7-proven 128x128 structure): C = epi(A[Mx512] @ Bt[Nx512]^T)
// Flat 1-D grid + bijective XCD swizzle; rowblk = swz>>gxShift (T1, verified R7:
// FETCH 202->37 MB). srcH resid and Ch both use ldh stride.
template<int EPI>
__global__ __launch_bounds__(256, 4) void gemm_k(
    const u16* __restrict__ A, const u16* __restrict__ Bt,
    float* __restrict__ Cf, u16* __restrict__ Ch,
    const u16* __restrict__ srcH,
    const float* __restrict__ bias, const float* __restrict__ bias2,
    const int* __restrict__ deg, const float* __restrict__ river,
    const float* __restrict__ w1tail, int Mreal, int ldh, int gxShift,
    float degScale)
{
    __shared__ __align__(16) u16 As[128 * 32];
    __shared__ __align__(16) u16 Bs[128 * 32];

    const int nwg  = gridDim.x;
    const int orig = blockIdx.x;
    const int xcd  = orig & 7;
    const int i8   = orig >> 3;
    const int q    = nwg >> 3;
    const int rm   = nwg & 7;
    const int swz  = (xcd < rm) ? (xcd * (q + 1) + i8)
                                : (rm * (q + 1) + (xcd - rm) * q + i8);
    const int rowblk = swz >> gxShift;
    const int colblk = swz & ((1 << gxShift) - 1);

    const int tid  = threadIdx.x;
    const int lane = tid & 63;
    const int wid  = tid >> 6;
    const int wr   = wid >> 1;
    const int wc   = wid & 1;
    const int fr   = lane & 15;
    const int fq   = lane >> 4;

    const long arow = (long)rowblk * 128 + (wid << 4) + (lane >> 2);
    const long brow = (long)colblk * 128 + (wid << 4) + (lane >> 2);
    const int  kofs = (lane & 3) << 3;
    u16* asw = As + (wid << 9);
    u16* bsw = Bs + (wid << 9);

    f32x4 acc[4][4];
#pragma unroll
    for (int m = 0; m < 4; m++)
#pragma unroll
        for (int n = 0; n < 4; n++) { f32x4 z = {0.f, 0.f, 0.f, 0.f}; acc[m][n] = z; }

    for (int kt = 0; kt < 512; kt += 32) {
        gl2lds16(A  + arow * 512 + kt + kofs,        asw);
        gl2lds16(A  + (arow + 64) * 512 + kt + kofs, asw + 2048);
        gl2lds16(Bt + brow * 512 + kt + kofs,        bsw);
        gl2lds16(Bt + (brow + 64) * 512 + kt + kofs, bsw + 2048);
        __syncthreads();

        s16x8 af[4], bf[4];
#pragma unroll
        for (int m = 0; m < 4; m++)
            af[m] = *(const s16x8*)(As + (((wr << 6) + (m << 4) + fr) << 5) + (fq << 3));
#pragma unroll
        for (int n = 0; n < 4; n++)
            bf[n] = *(const s16x8*)(Bs + (((wc << 6) + (n << 4) + fr) << 5) + (fq << 3));
#pragma unroll
        for (int m = 0; m < 4; m++)
#pragma unroll
            for (int n = 0; n < 4; n++)
                acc[m][n] = __builtin_amdgcn_mfma_f32_16x16x32_bf16(af[m], bf[n], acc[m][n], 0, 0, 0);
        __syncthreads();
    }

    const int colbase = (colblk << 7) + (wc << 6);
#pragma unroll
    for (int m = 0; m < 4; m++) {
        const int row0 = (rowblk << 7) + (wr << 6) + (m << 4) + (fq << 2);
#pragma unroll
        for (int rI = 0; rI < 4; rI++) {
            const int rr = row0 + rI;
            const bool real = rr < Mreal;
            float rv0 = 0.f, rv1 = 0.f, rv2 = 0.f;
            if constexpr (EPI & F_RANK3) {
                if (real) { rv0 = river[rr * 3]; rv1 = river[rr * 3 + 1]; rv2 = river[rr * 3 + 2]; }
            }
            float dg = 0.f;
            if constexpr (EPI & F_DEG) { if (real) dg = (float)deg[rr] * degScale; }
#pragma unroll
            for (int n = 0; n < 4; n++) {
                const int col = colbase + (n << 4) + fr;
                float v = acc[m][n][rI];
                if constexpr (EPI & F_BIAS)   v += bias[col];
                if constexpr (EPI & F_RANK3)  v += rv0 * w1tail[col] + rv1 * w1tail[512 + col] + rv2 * w1tail[1024 + col];
                if constexpr (EPI & F_GELU)   v = gelu_f(v);
                if constexpr (EPI & F_RESIDH) v += b2f(srcH[(long)rr * ldh + col]);
                if constexpr (EPI & F_DEG)    v += dg * bias2[col];
                if constexpr (EPI & F_OUTF)   { if (real) Cf[(long)rr * 512 + col] = v; }
                if constexpr (EPI & F_OUTH)   Ch[(long)rr * ldh + col] = f2b(v);
            }
        }
    }
}

// ---------- CSR build ----------
__global__ __launch_bounds__(256) void deg_k(const int* __restrict__ ed, int* __restrict__ deg, int nE)
{
    const int e = blockIdx.x * 256 + threadIdx.x;
    if (e < nE) atomicAdd(&deg[ed[2 * e + 1]], 1);
}

__global__ __launch_bounds__(256) void scan1_k(
    const int* __restrict__ deg, int* __restrict__ rowptr,
    int* __restrict__ partials, int n)
{
    __shared__ int tmp[256];
    const int tid = threadIdx.x;
    const int gid = blockIdx.x * 256 + tid;
    const int v = (gid < n) ? deg[gid] : 0;
    tmp[tid] = v;
    __syncthreads();
#pragma unroll
    for (int ofs = 1; ofs < 256; ofs <<= 1) {
        int t = (tid >= ofs) ? tmp[tid - ofs] : 0;
        __syncthreads();
        tmp[tid] += t;
        __syncthreads();
    }
    if (gid < n) rowptr[gid] = tmp[tid] - v;
    if (tid == 255) partials[blockIdx.x] = tmp[255];
}

__global__ __launch_bounds__(256) void scan2_k(int* __restrict__ partials, int nb)
{
    __shared__ int tmp[256];
    const int tid = threadIdx.x;
    const int v = (tid < nb) ? partials[tid] : 0;
    tmp[tid] = v;
    __syncthreads();
#pragma unroll
    for (int ofs = 1; ofs < 256; ofs <<= 1) {
        int t = (tid >= ofs) ? tmp[tid - ofs] : 0;
        __syncthreads();
        tmp[tid] += t;
        __syncthreads();
    }
    if (tid < nb) partials[tid] = tmp[tid] - v;
}

__global__ __launch_bounds__(256) void scan3_k(
    int* __restrict__ rowptr, const int* __restrict__ partials, int n)
{
    const int gid = blockIdx.x * 256 + threadIdx.x;
    if (gid < n) rowptr[gid] += partials[blockIdx.x];
}

__global__ __launch_bounds__(256) void scat_k(
    const int* __restrict__ ed, const int* __restrict__ rowptr,
    int* __restrict__ cursor, int* __restrict__ csr, int nE)
{
    const int e = blockIdx.x * 256 + threadIdx.x;
    if (e >= nE) return;
    const int t = ed[2 * e + 1];
    const int p = atomicAdd(&cursor[t], 1);
    csr[rowptr[t] + p] = ed[2 * e];
}

// ---------- gather: acc[t] = sum_{s in in(t)} gelu(A[s] + B[t] + bm1)
// Hg (optional): fresh bf16 result. Hsum (optional): bf16 running sum
// (accum=0: overwrite; accum=1: Hsum += acc).
__global__ __launch_bounds__(256) void gather_k(
    const int* __restrict__ rowptr, const int* __restrict__ degv,
    const int* __restrict__ csr, const u16* __restrict__ AB,
    const float* __restrict__ bm1, u16* __restrict__ Hg,
    u16* __restrict__ Hsum, int accum, int nNodes)
{
    const int t = (blockIdx.x << 2) + (threadIdx.x >> 6);
    if (t >= nNodes) return;
    const int lane = threadIdx.x & 63;
    const int c = lane << 3;
    float acc[8] = {0.f, 0.f, 0.f, 0.f, 0.f, 0.f, 0.f, 0.f};
    const int d = degv[t];
    if (d > 0) {
        s16x8 bv = *(const s16x8*)(AB + (long)t * 1024 + 512 + c);
        const float4* bmv = (const float4*)(bm1 + c);
        float4 q0 = bmv[0], q1 = bmv[1];
        float base[8] = { q0.x, q0.y, q0.z, q0.w, q1.x, q1.y, q1.z, q1.w };
#pragma unroll
        for (int j = 0; j < 8; j++) base[j] += b2f((u16)bv[j]);
        const int p0 = rowptr[t];
        for (int i = 0; i < d; i++) {
            const int s = csr[p0 + i];
            s16x8 av = *(const s16x8*)(AB + (long)s * 1024 + c);
#pragma unroll
            for (int j = 0; j < 8; j++) acc[j] += gelu_f(b2f((u16)av[j]) + base[j]);
        }
    }
    if (Hg) {
        s16x8 o;
#pragma unroll
        for (int j = 0; j < 8; j++) o[j] = (short)f2b(acc[j]);
        *(s16x8*)(Hg + (long)t * 512 + c) = o;
    }
    if (Hsum) {
        s16x8 o;
        if (accum) {
            s16x8 old = *(const s16x8*)(Hsum + (long)t * 512 + c);
#pragma unroll
            for (int j = 0; j < 8; j++) o[j] = (short)f2b(b2f((u16)old[j]) + acc[j]);
        } else {
#pragma unroll
            for (int j = 0; j < 8; j++) o[j] = (short)f2b(acc[j]);
        }
        *(s16x8*)(Hsum + (long)t * 512 + c) = o;
    }
}

// ---------- f32 -> bf16 (flat, region beyond nSrc zero-filled) ----------
__global__ __launch_bounds__(256) void cvt_pad_k(
    const float* __restrict__ src, u16* __restrict__ dst, long nSrc, long nTot)
{
    const long i = ((long)blockIdx.x * 256 + threadIdx.x) * 8;
    if (i >= nTot) return;
    s16x8 v;
    if (i + 8 <= nSrc) {
        const float4* s4 = (const float4*)(src + i);
        float4 a = s4[0], b = s4[1];
        v[0] = (short)f2b(a.x); v[1] = (short)f2b(a.y); v[2] = (short)f2b(a.z); v[3] = (short)f2b(a.w);
        v[4] = (short)f2b(b.x); v[5] = (short)f2b(b.y); v[6] = (short)f2b(b.z); v[7] = (short)f2b(b.w);
    } else {
#pragma unroll
        for (int j = 0; j < 8; j++) v[j] = (i + j < nSrc) ? (short)f2b(src[i + j]) : (short)0;
    }
    *(s16x8*)(dst + i) = v;
}

// ---------- weight transpose + convert: Wt[n*K+k] = bf16(W[(k+off)*N + n]) ----------
__global__ __launch_bounds__(256) void wtrans_k(
    const float* __restrict__ W, u16* __restrict__ Wt, int K, int N, int rowOff)
{
    const int idx = blockIdx.x * 256 + threadIdx.x;
    if (idx >= K * N) return;
    const int n = idx / K, k = idx % K;
    Wt[idx] = f2b(W[(long)(k + rowOff) * N + n]);
}

// ---------- bfuse[j] = sum_k bm2[k] * Wm1c[k][j]  (Wm1ct[j][k] bf16) ----------
__global__ __launch_bounds__(256) void bfuse_k(
    const float* __restrict__ bm2, const u16* __restrict__ Wm1ct,
    float* __restrict__ bfuse)
{
    const int j = blockIdx.x * 256 + threadIdx.x;
    if (j >= 1024) return;
    float s = 0.f;
    const u16* row = Wm1ct + (long)j * 512;
    for (int k = 0; k < 512; k += 8) {
        s16x8 w = *(const s16x8*)(row + k);
#pragma unroll
        for (int u = 0; u < 8; u++) s += bm2[k + u] * b2f((u16)w[u]);
    }
    bfuse[j] = s;
}

extern "C" void kernel_launch(void* const* d_in, const int* in_sizes, int n_in,
                              void* d_out, int out_size, void* d_ws, size_t ws_size,
                              hipStream_t stream)
{
    const float* nodef = (const float*)d_in[0];
    const float* river = (const float*)d_in[1];
    const int*   edges = (const int*)d_in[2];
    const float* W1  = (const float*)d_in[3];
    const float* b1  = (const float*)d_in[4];
    const float* W2  = (const float*)d_in[5];
    const float* b2  = (const float*)d_in[6];
    const float* Wm1 = (const float*)d_in[7];
    const float* bm1 = (const float*)d_in[8];
    const float* Wm2 = (const float*)d_in[9];
    const float* bm2 = (const float*)d_in[10];
    float* out = (float*)d_out;
    (void)n_in; (void)out_size;

    const int M = 50000, Mpad = 50048, H = 512;
    const int nE = in_sizes[2] / 2;
    const size_t nElem = (size_t)Mpad * H;
    const size_t nOut  = (size_t)M * H;

    char* ws = (char*)d_ws;
    size_t off = 0;
    auto alloc = [&](size_t bytes) { void* p = ws + off; off += (bytes + 255) & ~(size_t)255; return p; };
    u16* feats16 = (u16*)alloc(nElem * 2);            // feats0 (bf16)
    u16* AB16    = (u16*)alloc(nElem * 4);            // [Mpad][1024]: A | B (nf16 early)
    u16* Hg16    = (u16*)alloc(nElem * 2);            // h1 / fresh gather output
    u16* W1t     = (u16*)alloc(512 * 512 * 2);
    u16* W2t     = (u16*)alloc(512 * 512 * 2);
    u16* Wm1ct   = (u16*)alloc(1024 * 512 * 2);
    u16* Wm2t    = (u16*)alloc(512 * 512 * 2);
    int* deg     = (int*)alloc((size_t)Mpad * 4);
    int* rowptr  = (int*)alloc((size_t)Mpad * 4);
    int* cursor  = (int*)alloc((size_t)Mpad * 4);
    int* csr     = (int*)alloc((size_t)nE * 4);
    int* partials= (int*)alloc(256 * 4);
    const size_t NEED_BASE = off;                     // ~209 MB (confirmed fits, R3+)
    u16* Hsum16  = (u16*)alloc(nElem * 2);            // running sum of Hg
    u16* Wfuset  = (u16*)alloc(1024 * 512 * 2);       // (Wm2 @ Wm1c)^T bf16
    u16* Wm2nt   = (u16*)alloc(512 * 512 * 2);        // Wm2 row-major bf16 (NOT transposed)
    float* bfuse = (float*)alloc(1024 * 4);           // bm2 @ Wm1c
    const size_t NEED_FUSED = off;                    // ~262 MB (confirmed: R9 ran fused)

    if (ws_size < NEED_BASE) return;                  // tripwire: clean absmax fail
    const bool fused = ws_size >= NEED_FUSED;

    const int scanBlocks = (Mpad + 255) / 256;        // 196
    const int MB = Mpad / 128;                        // 391
    const dim3 g512(MB * 4, 1, 1);                    // gxShift=2
    const dim3 g1024(MB * 8, 1, 1);                   // gxShift=3
    const dim3 gtiny(32, 1, 1);                       // M=1024, N=512 -> 8x4, gxShift=2
    const dim3 gblk(256, 1, 1);
    const int cvtBlocks = (int)(nElem / 8 / 256);

    // CSR build
    hipMemsetAsync(deg, 0, (size_t)Mpad * 4, stream);
    hipMemsetAsync(cursor, 0, (size_t)Mpad * 4, stream);
    deg_k<<<dim3((nE + 255) / 256), gblk, 0, stream>>>(edges, deg, nE);
    scan1_k<<<dim3(scanBlocks), gblk, 0, stream>>>(deg, rowptr, partials, Mpad);
    scan2_k<<<dim3(1), gblk, 0, stream>>>(partials, scanBlocks);
    scan3_k<<<dim3(scanBlocks), gblk, 0, stream>>>(rowptr, partials, Mpad);
    scat_k<<<dim3((nE + 255) / 256), gblk, 0, stream>>>(edges, rowptr, cursor, csr, nE);

    // weights -> transposed bf16
    wtrans_k<<<dim3(1024), gblk, 0, stream>>>(W1,  W1t,             512, 512, 0);
    wtrans_k<<<dim3(1024), gblk, 0, stream>>>(W2,  W2t,             512, 512, 0);
    wtrans_k<<<dim3(1024), gblk, 0, stream>>>(Wm1, Wm1ct,           512, 512, 0);
    wtrans_k<<<dim3(1024), gblk, 0, stream>>>(Wm1, Wm1ct + 512*512, 512, 512, 512);
    wtrans_k<<<dim3(1024), gblk, 0, stream>>>(Wm2, Wm2t,            512, 512, 0);

    // node_features -> bf16 (flat [Mpad][512] in AB16 first half)
    cvt_pad_k<<<dim3(cvtBlocks), gblk, 0, stream>>>(nodef, AB16, (long)nOut, (long)nElem);

    // h1 = gelu(x @ W1 + b1 + river term) -> Hg16
    gemm_k<F_BIAS | F_RANK3 | F_GELU | F_OUTH><<<g512, gblk, 0, stream>>>(
        AB16, W1t, nullptr, Hg16, nullptr, b1, nullptr, nullptr, river, W1 + 512 * 512, M, 512, 2, 1.f);
    // feats0 = h1 @ W2 + b2 -> feats16
    gemm_k<F_BIAS | F_OUTH><<<g512, gblk, 0, stream>>>(
        Hg16, W2t, nullptr, feats16, nullptr, b2, nullptr, nullptr, nullptr, nullptr, M, 512, 2, 1.f);

    if (fused) {
        // Wm2 -> bf16 row-major (flat convert, no transpose): Wm2nt[i][k] = Wm2[i][k]
        cvt_pad_k<<<dim3(128), gblk, 0, stream>>>(Wm2, Wm2nt, 512 * 512, 512 * 512);
        // Wfuset[j][i] = sum_k Wm1ct[j][k] * Wm2nt[i][k] = sum_k Wm1c[k][j]*Wm2[i][k]
        gemm_k<F_OUTH><<<gtiny, gblk, 0, stream>>>(
            Wm1ct, Wm2nt, nullptr, Wfuset, nullptr, nullptr, nullptr, nullptr, nullptr, nullptr, 1024, 512, 2, 1.f);
        bfuse_k<<<dim3(4), gblk, 0, stream>>>(bm2, Wm1ct, bfuse);

        // AB0 = feats0 @ [Wm1a|Wm1b]
        gemm_k<F_OUTH><<<g1024, gblk, 0, stream>>>(
            feats16, Wm1ct, nullptr, AB16, nullptr, nullptr, nullptr, nullptr, nullptr, nullptr, M, 1024, 3, 1.f);
        // r=0: gather -> Hsum (write); AB1 = AB0 + Hsum @ Wfuse + deg*bfuse
        gather_k<<<dim3(Mpad / 4), gblk, 0, stream>>>(rowptr, deg, csr, AB16, bm1, nullptr, Hsum16, 0, Mpad);
        gemm_k<F_RESIDH | F_DEG | F_OUTH><<<g1024, gblk, 0, stream>>>(
            Hsum16, Wfuset, nullptr, AB16, AB16, nullptr, bfuse, deg, nullptr, nullptr, M, 1024, 3, 1.f);
        // r=1: gather -> Hg (fresh) + Hsum += ; AB2 = AB1 + Hg @ Wfuse + deg*bfuse
        gather_k<<<dim3(Mpad / 4), gblk, 0, stream>>>(rowptr, deg, csr, AB16, bm1, Hg16, Hsum16, 1, Mpad);
        gemm_k<F_RESIDH | F_DEG | F_OUTH><<<g1024, gblk, 0, stream>>>(
            Hg16, Wfuset, nullptr, AB16, AB16, nullptr, bfuse, deg, nullptr, nullptr, M, 1024, 3, 1.f);
        // r=2: gather -> Hsum +=
        gather_k<<<dim3(Mpad / 4), gblk, 0, stream>>>(rowptr, deg, csr, AB16, bm1, nullptr, Hsum16, 1, Mpad);
        // out = feats0 + Hsum @ Wm2 + 3*deg*bm2
        gemm_k<F_RESIDH | F_DEG | F_OUTF><<<g512, gblk, 0, stream>>>(
            Hsum16, Wm2t, out, nullptr, feats16, nullptr, bm2, deg, nullptr, nullptr, M, 512, 2, 3.f);
    } else {
        // R7 fallback pipeline
        for (int r = 0; r < 3; r++) {
            gemm_k<F_OUTH><<<g1024, gblk, 0, stream>>>(
                feats16, Wm1ct, nullptr, AB16, nullptr, nullptr, nullptr, nullptr, nullptr, nullptr, M, 1024, 3, 1.f);
            gather_k<<<dim3(Mpad / 4), gblk, 0, stream>>>(rowptr, deg, csr, AB16, bm1, Hg16, nullptr, 0, Mpad);
            if (r < 2)
                gemm_k<F_RESIDH | F_DEG | F_OUTH><<<g512, gblk, 0, stream>>>(
                    Hg16, Wm2t, nullptr, feats16, feats16, nullptr, bm2, deg, nullptr, nullptr, M, 512, 2, 1.f);
            else
                gemm_k<F_RESIDH | F_DEG | F_OUTF><<<g512, gblk, 0, stream>>>(
                    Hg16, Wm2t, out, nullptr, feats16, nullptr, bm2, deg, nullptr, nullptr, M, 512, 2, 1.f);
        }
    }
}

// Round 11
// 665.304 us; speedup vs baseline: 1.0948x; 1.0373x over previous
//
#include <hip/hip_runtime.h>
#include <hip/hip_bf16.h>
#include <cstdint>

using u16 = unsigned short;
typedef short s16x8 __attribute__((ext_vector_type(8)));
typedef float f32x4 __attribute__((ext_vector_type(4)));

// ---------- helpers ----------
__device__ __forceinline__ float b2f(u16 b) {
    union { unsigned u; float f; } z; z.u = ((unsigned)b) << 16; return z.f;
}
__device__ __forceinline__ u16 f2b(float f) {
    union { float f; unsigned u; } z; z.f = f;
    return (u16)((z.u + 0x7fffu + ((z.u >> 16) & 1u)) >> 16);
}
__device__ __forceinline__ float gelu_f(float x) {
    return 0.5f * x * (1.0f + erff(x * 0.70710678118654752440f));
}
__device__ __forceinline__ void gl2lds16(const void* g, void* l) {
    __builtin_amdgcn_global_load_lds(
        (const __attribute__((address_space(1))) void*)g,
        (__attribute__((address_space(3))) void*)l, 16, 0, 0);
}

enum { F_BIAS = 1, F_GELU = 2, F_RANK3 = 4, F_RESIDH = 8,
       F_DEG = 16, F_OUTF = 32, F_OUTH = 64 };

// ---------- GEMM 128x128, BK=64: C = epi(A[Mx512] @ Bt[Nx512]^T) ----------
// vs R7 (BK=32): half the K-iterations -> half the barrier/vmcnt(0) drains
// (the documented ~20% structural stall), LDS still 32 KB -> 4 blocks/CU.
// LDS rows are 128 B; stored chunk c holds global chunk c^(row&7) (R8-verified
// swizzle: conflicts 6.4M -> 0). global_load_lds dest is linear (rule #21:
// swizzle applied on the per-lane GLOBAL source + on ds_read address).
// T1 bijective XCD swizzle kept (R7-verified: FETCH 202->37 MB).
template<int EPI>
__global__ __launch_bounds__(256, 4) void gemm_k(
    const u16* __restrict__ A, const u16* __restrict__ Bt,
    float* __restrict__ Cf, u16* __restrict__ Ch,
    const u16* __restrict__ srcH,
    const float* __restrict__ bias, const float* __restrict__ bias2,
    const int* __restrict__ deg, const float* __restrict__ river,
    const float* __restrict__ w1tail, int Mreal, int ldh, int gxShift,
    float degScale)
{
    __shared__ __align__(16) u16 As[128 * 64];   // 16 KB
    __shared__ __align__(16) u16 Bs[128 * 64];   // 16 KB

    const int nwg  = gridDim.x;
    const int orig = blockIdx.x;
    const int xcd  = orig & 7;
    const int i8   = orig >> 3;
    const int q    = nwg >> 3;
    const int rm   = nwg & 7;
    const int swz  = (xcd < rm) ? (xcd * (q + 1) + i8)
                                : (rm * (q + 1) + (xcd - rm) * q + i8);
    const int rowblk = swz >> gxShift;
    const int colblk = swz & ((1 << gxShift) - 1);

    const int tid  = threadIdx.x;
    const int lane = tid & 63;
    const int wid  = tid >> 6;     // 0..3
    const int wr   = wid >> 1;
    const int wc   = wid & 1;
    const int fr   = lane & 15;
    const int fq   = lane >> 4;

    // staging: wave wid owns rows [wid*32, wid*32+32); issue j covers 8 rows.
    // lane l -> row (l>>3), stored chunk (l&7); global chunk = (l&7)^(row&7).
    const int  srowl = lane >> 3;                       // 0..7 within issue
    const long gchnk = (long)(((lane & 7) ^ (srowl & 7)) << 3);  // elem offset
    const long abase = (long)rowblk * 128 + (wid << 5) + srowl;
    const long bbase = (long)colblk * 128 + (wid << 5) + srowl;
    u16* asw = As + (wid << 11);                        // wid*32*64 elems
    u16* bsw = Bs + (wid << 11);

    f32x4 acc[4][4];
#pragma unroll
    for (int m = 0; m < 4; m++)
#pragma unroll
        for (int n = 0; n < 4; n++) { f32x4 z = {0.f, 0.f, 0.f, 0.f}; acc[m][n] = z; }

    for (int kt = 0; kt < 8; kt++) {
        const long ko = (long)(kt << 6) + gchnk;
#pragma unroll
        for (int j = 0; j < 4; j++) {
            gl2lds16(A  + (abase + (j << 3)) * 512 + ko, asw + (j << 9));
            gl2lds16(Bt + (bbase + (j << 3)) * 512 + ko, bsw + (j << 9));
        }
        __syncthreads();

#pragma unroll
        for (int ks = 0; ks < 2; ks++) {
            const int sc = ((((ks << 2) + fq) ^ (fr & 7)) << 3);  // swizzled chunk
            s16x8 af[4], bf[4];
#pragma unroll
            for (int m = 0; m < 4; m++)
                af[m] = *(const s16x8*)(As + (((wr << 6) + (m << 4) + fr) << 6) + sc);
#pragma unroll
            for (int n = 0; n < 4; n++)
                bf[n] = *(const s16x8*)(Bs + (((wc << 6) + (n << 4) + fr) << 6) + sc);
#pragma unroll
            for (int m = 0; m < 4; m++)
#pragma unroll
                for (int n = 0; n < 4; n++)
                    acc[m][n] = __builtin_amdgcn_mfma_f32_16x16x32_bf16(af[m], bf[n], acc[m][n], 0, 0, 0);
        }
        __syncthreads();
    }

    const int colbase = (colblk << 7) + (wc << 6);
#pragma unroll
    for (int m = 0; m < 4; m++) {
        const int row0 = (rowblk << 7) + (wr << 6) + (m << 4) + (fq << 2);
#pragma unroll
        for (int rI = 0; rI < 4; rI++) {
            const int rr = row0 + rI;
            const bool real = rr < Mreal;
            float rv0 = 0.f, rv1 = 0.f, rv2 = 0.f;
            if constexpr (EPI & F_RANK3) {
                if (real) { rv0 = river[rr * 3]; rv1 = river[rr * 3 + 1]; rv2 = river[rr * 3 + 2]; }
            }
            float dg = 0.f;
            if constexpr (EPI & F_DEG) { if (real) dg = (float)deg[rr] * degScale; }
#pragma unroll
            for (int n = 0; n < 4; n++) {
                const int col = colbase + (n << 4) + fr;
                float v = acc[m][n][rI];
                if constexpr (EPI & F_BIAS)   v += bias[col];
                if constexpr (EPI & F_RANK3)  v += rv0 * w1tail[col] + rv1 * w1tail[512 + col] + rv2 * w1tail[1024 + col];
                if constexpr (EPI & F_GELU)   v = gelu_f(v);
                if constexpr (EPI & F_RESIDH) v += b2f(srcH[(long)rr * ldh + col]);
                if constexpr (EPI & F_DEG)    v += dg * bias2[col];
                if constexpr (EPI & F_OUTF)   { if (real) Cf[(long)rr * 512 + col] = v; }
                if constexpr (EPI & F_OUTH)   Ch[(long)rr * ldh + col] = f2b(v);
            }
        }
    }
}

// ---------- CSR build ----------
__global__ __launch_bounds__(256) void deg_k(const int* __restrict__ ed, int* __restrict__ deg, int nE)
{
    const int e = blockIdx.x * 256 + threadIdx.x;
    if (e < nE) atomicAdd(&deg[ed[2 * e + 1]], 1);
}

__global__ __launch_bounds__(256) void scan1_k(
    const int* __restrict__ deg, int* __restrict__ rowptr,
    int* __restrict__ partials, int n)
{
    __shared__ int tmp[256];
    const int tid = threadIdx.x;
    const int gid = blockIdx.x * 256 + tid;
    const int v = (gid < n) ? deg[gid] : 0;
    tmp[tid] = v;
    __syncthreads();
#pragma unroll
    for (int ofs = 1; ofs < 256; ofs <<= 1) {
        int t = (tid >= ofs) ? tmp[tid - ofs] : 0;
        __syncthreads();
        tmp[tid] += t;
        __syncthreads();
    }
    if (gid < n) rowptr[gid] = tmp[tid] - v;
    if (tid == 255) partials[blockIdx.x] = tmp[255];
}

__global__ __launch_bounds__(256) void scan2_k(int* __restrict__ partials, int nb)
{
    __shared__ int tmp[256];
    const int tid = threadIdx.x;
    const int v = (tid < nb) ? partials[tid] : 0;
    tmp[tid] = v;
    __syncthreads();
#pragma unroll
    for (int ofs = 1; ofs < 256; ofs <<= 1) {
        int t = (tid >= ofs) ? tmp[tid - ofs] : 0;
        __syncthreads();
        tmp[tid] += t;
        __syncthreads();
    }
    if (tid < nb) partials[tid] = tmp[tid] - v;
}

__global__ __launch_bounds__(256) void scan3_k(
    int* __restrict__ rowptr, const int* __restrict__ partials, int n)
{
    const int gid = blockIdx.x * 256 + threadIdx.x;
    if (gid < n) rowptr[gid] += partials[blockIdx.x];
}

__global__ __launch_bounds__(256) void scat_k(
    const int* __restrict__ ed, const int* __restrict__ rowptr,
    int* __restrict__ cursor, int* __restrict__ csr, int nE)
{
    const int e = blockIdx.x * 256 + threadIdx.x;
    if (e >= nE) return;
    const int t = ed[2 * e + 1];
    const int p = atomicAdd(&cursor[t], 1);
    csr[rowptr[t] + p] = ed[2 * e];
}

// ---------- gather: Hg[t] = bf16( sum_{s in in(t)} gelu(A[s] + B[t] + bm1) ) ----------
__global__ __launch_bounds__(256) void gather_k(
    const int* __restrict__ rowptr, const int* __restrict__ degv,
    const int* __restrict__ csr, const u16* __restrict__ AB,
    const float* __restrict__ bm1, u16* __restrict__ Hg, int nNodes)
{
    const int t = (blockIdx.x << 2) + (threadIdx.x >> 6);
    if (t >= nNodes) return;
    const int lane = threadIdx.x & 63;
    const int c = lane << 3;
    float acc[8] = {0.f, 0.f, 0.f, 0.f, 0.f, 0.f, 0.f, 0.f};
    const int d = degv[t];
    if (d > 0) {
        s16x8 bv = *(const s16x8*)(AB + (long)t * 1024 + 512 + c);
        const float4* bmv = (const float4*)(bm1 + c);
        float4 q0 = bmv[0], q1 = bmv[1];
        float base[8] = { q0.x, q0.y, q0.z, q0.w, q1.x, q1.y, q1.z, q1.w };
#pragma unroll
        for (int j = 0; j < 8; j++) base[j] += b2f((u16)bv[j]);
        const int p0 = rowptr[t];
        for (int i = 0; i < d; i++) {
            const int s = csr[p0 + i];
            s16x8 av = *(const s16x8*)(AB + (long)s * 1024 + c);
#pragma unroll
            for (int j = 0; j < 8; j++) acc[j] += gelu_f(b2f((u16)av[j]) + base[j]);
        }
    }
    s16x8 o;
#pragma unroll
    for (int j = 0; j < 8; j++) o[j] = (short)f2b(acc[j]);
    *(s16x8*)(Hg + (long)t * 512 + c) = o;
}

// ---------- f32 -> bf16 (flat, region beyond nSrc zero-filled) ----------
__global__ __launch_bounds__(256) void cvt_pad_k(
    const float* __restrict__ src, u16* __restrict__ dst, long nSrc, long nTot)
{
    const long i = ((long)blockIdx.x * 256 + threadIdx.x) * 8;
    if (i >= nTot) return;
    s16x8 v;
    if (i + 8 <= nSrc) {
        const float4* s4 = (const float4*)(src + i);
        float4 a = s4[0], b = s4[1];
        v[0] = (short)f2b(a.x); v[1] = (short)f2b(a.y); v[2] = (short)f2b(a.z); v[3] = (short)f2b(a.w);
        v[4] = (short)f2b(b.x); v[5] = (short)f2b(b.y); v[6] = (short)f2b(b.z); v[7] = (short)f2b(b.w);
    } else {
#pragma unroll
        for (int j = 0; j < 8; j++) v[j] = (i + j < nSrc) ? (short)f2b(src[i + j]) : (short)0;
    }
    *(s16x8*)(dst + i) = v;
}

// ---------- weight transpose + convert: Wt[n*K+k] = bf16(W[(k+off)*N + n]) ----------
__global__ __launch_bounds__(256) void wtrans_k(
    const float* __restrict__ W, u16* __restrict__ Wt, int K, int N, int rowOff)
{
    const int idx = blockIdx.x * 256 + threadIdx.x;
    if (idx >= K * N) return;
    const int n = idx / K, k = idx % K;
    Wt[idx] = f2b(W[(long)(k + rowOff) * N + n]);
}

extern "C" void kernel_launch(void* const* d_in, const int* in_sizes, int n_in,
                              void* d_out, int out_size, void* d_ws, size_t ws_size,
                              hipStream_t stream)
{
    const float* nodef = (const float*)d_in[0];
    const float* river = (const float*)d_in[1];
    const int*   edges = (const int*)d_in[2];
    const float* W1  = (const float*)d_in[3];
    const float* b1  = (const float*)d_in[4];
    const float* W2  = (const float*)d_in[5];
    const float* b2  = (const float*)d_in[6];
    const float* Wm1 = (const float*)d_in[7];
    const float* bm1 = (const float*)d_in[8];
    const float* Wm2 = (const float*)d_in[9];
    const float* bm2 = (const float*)d_in[10];
    float* out = (float*)d_out;
    (void)n_in; (void)out_size;

    const int M = 50000, Mpad = 50048, H = 512;
    const int nE = in_sizes[2] / 2;
    const size_t nElem = (size_t)Mpad * H;
    const size_t nOut  = (size_t)M * H;

    char* ws = (char*)d_ws;
    size_t off = 0;
    auto alloc = [&](size_t bytes) { void* p = ws + off; off += (bytes + 255) & ~(size_t)255; return p; };
    u16* feats16 = (u16*)alloc(nElem * 2);            // running features (bf16 residual carrier)
    u16* AB16    = (u16*)alloc(nElem * 4);            // [Mpad][1024]: A | B (nf16 early)
    u16* Hg16    = (u16*)alloc(nElem * 2);            // gather output / h1
    u16* W1t     = (u16*)alloc(512 * 512 * 2);
    u16* W2t     = (u16*)alloc(512 * 512 * 2);
    u16* Wm1ct   = (u16*)alloc(1024 * 512 * 2);
    u16* Wm2t    = (u16*)alloc(512 * 512 * 2);
    int* deg     = (int*)alloc((size_t)Mpad * 4);
    int* rowptr  = (int*)alloc((size_t)Mpad * 4);
    int* cursor  = (int*)alloc((size_t)Mpad * 4);
    int* csr     = (int*)alloc((size_t)nE * 4);
    int* partials= (int*)alloc(256 * 4);
    const size_t NEED = off;                          // ~209 MB (confirmed fits)

    if (ws_size < NEED) return;                       // tripwire: clean absmax fail

    const int scanBlocks = (Mpad + 255) / 256;        // 196
    const int MB = Mpad / 128;                        // 391
    const dim3 g512(MB * 4, 1, 1);                    // gxShift=2
    const dim3 g1024(MB * 8, 1, 1);                   // gxShift=3
    const dim3 gblk(256, 1, 1);
    const int cvtBlocks = (int)(nElem / 8 / 256);

    // CSR build (edges fixed; rebuilt every call for determinism)
    hipMemsetAsync(deg, 0, (size_t)Mpad * 4, stream);
    hipMemsetAsync(cursor, 0, (size_t)Mpad * 4, stream);
    deg_k<<<dim3((nE + 255) / 256), gblk, 0, stream>>>(edges, deg, nE);
    scan1_k<<<dim3(scanBlocks), gblk, 0, stream>>>(deg, rowptr, partials, Mpad);
    scan2_k<<<dim3(1), gblk, 0, stream>>>(partials, scanBlocks);
    scan3_k<<<dim3(scanBlocks), gblk, 0, stream>>>(rowptr, partials, Mpad);
    scat_k<<<dim3((nE + 255) / 256), gblk, 0, stream>>>(edges, rowptr, cursor, csr, nE);

    // weights -> transposed bf16
    wtrans_k<<<dim3(1024), gblk, 0, stream>>>(W1,  W1t,             512, 512, 0);
    wtrans_k<<<dim3(1024), gblk, 0, stream>>>(W2,  W2t,             512, 512, 0);
    wtrans_k<<<dim3(1024), gblk, 0, stream>>>(Wm1, Wm1ct,           512, 512, 0);
    wtrans_k<<<dim3(1024), gblk, 0, stream>>>(Wm1, Wm1ct + 512*512, 512, 512, 512);
    wtrans_k<<<dim3(1024), gblk, 0, stream>>>(Wm2, Wm2t,            512, 512, 0);

    // node_features -> bf16 (flat [Mpad][512] in AB16 first half)
    cvt_pad_k<<<dim3(cvtBlocks), gblk, 0, stream>>>(nodef, AB16, (long)nOut, (long)nElem);

    // h1 = gelu(x @ W1 + b1 + river term) -> Hg16
    gemm_k<F_BIAS | F_RANK3 | F_GELU | F_OUTH><<<g512, gblk, 0, stream>>>(
        AB16, W1t, nullptr, Hg16, nullptr, b1, nullptr, nullptr, river, W1 + 512 * 512, M, 512, 2, 1.f);
    // feats16 = h1 @ W2 + b2  (bf16 only)
    gemm_k<F_BIAS | F_OUTH><<<g512, gblk, 0, stream>>>(
        Hg16, W2t, nullptr, feats16, nullptr, b2, nullptr, nullptr, nullptr, nullptr, M, 512, 2, 1.f);

    for (int r = 0; r < 3; r++) {
        // AB = feats @ [Wm1_top | Wm1_bot]  (N=1024 combined)
        gemm_k<F_OUTH><<<g1024, gblk, 0, stream>>>(
            feats16, Wm1ct, nullptr, AB16, nullptr, nullptr, nullptr, nullptr, nullptr, nullptr, M, 1024, 3, 1.f);
        // Hg[t] = sum_in gelu(A[s] + B[t] + bm1)
        gather_k<<<dim3(Mpad / 4), gblk, 0, stream>>>(rowptr, deg, csr, AB16, bm1, Hg16, Mpad);
        // feats = feats + Hg @ Wm2 + deg * bm2
        if (r < 2)
            gemm_k<F_RESIDH | F_DEG | F_OUTH><<<g512, gblk, 0, stream>>>(
                Hg16, Wm2t, nullptr, feats16, feats16, nullptr, bm2, deg, nullptr, nullptr, M, 512, 2, 1.f);
        else
            gemm_k<F_RESIDH | F_DEG | F_OUTF><<<g512, gblk, 0, stream>>>(
                Hg16, Wm2t, out, nullptr, feats16, nullptr, bm2, deg, nullptr, nullptr, M, 512, 2, 1.f);
    }
}